// Round 3
// baseline (38.738 us; speedup 1.0000x reference)
//
#include <hip/hip_runtime.h>

#define VCNT 262144           // 64^3
#define NB 2
#define NT 128
#define HWPIX 65536           // 1*256*256

typedef float f32x2 __attribute__((ext_vector_type(2)));

// exp(u) on u in [0.009, 1.156]: degree-6 Taylor at c=0.5823 (a_k = e^c / k!).
// Max rel err ~1.3e-5 on w; cancels in w/sum(w) -> output err ~5e-8.
#define PC  0.5823f
#define PA0 1.7901520f
#define PA1 1.7901520f
#define PA2 0.8950760f
#define PA3 0.29835867f
#define PA4 0.07458967f
#define PA5 0.01491793f
#define PA6 0.00248632f

static __device__ __forceinline__ float fast_rsq(float x) {
#if __has_builtin(__builtin_amdgcn_rsqf)
    return __builtin_amdgcn_rsqf(x);
#else
    float r; asm("v_rsq_f32 %0, %1" : "=v"(r) : "v"(x)); return r;
#endif
}

// ---------------------------------------------------------------------------
// Kernel 0: needed-slice flags. One block, 256 threads.
// flags[b*128+t] = 1 iff slice (b,t) appears in slice_indices[b,:].
// ---------------------------------------------------------------------------
__global__ __launch_bounds__(256) void flags_kernel(
    const int* __restrict__ sidx, int* __restrict__ flags)
{
    const int i = threadIdx.x;        // 0..255 == b*NT+slot
    flags[i] = 0;
    __syncthreads();
    const int b = i >> 7;
    flags[(b << 7) + sidx[i]] = 1;    // duplicate stores of 1 are fine
}

// ---------------------------------------------------------------------------
// Kernel 1: partial slice sums, needed slices only.
// 8 blocks per slice -> 2048 blocks; unneeded slices early-exit uniformly.
// ---------------------------------------------------------------------------
__global__ __launch_bounds__(256) void slice_partial_kernel(
    const float* __restrict__ slices, const int* __restrict__ flags,
    float* __restrict__ partials)
{
    const int s = blockIdx.x >> 3;
    if (flags[s] == 0) return;        // block-uniform exit
    const int j = blockIdx.x & 7;
    const float4* p = (const float4*)(slices + (size_t)s * HWPIX) + j * 2048;

    float acc = 0.0f;
#pragma unroll
    for (int i = 0; i < 8; ++i) {
        float4 v = p[i * 256 + threadIdx.x];
        acc += (v.x + v.y) + (v.z + v.w);
    }
#pragma unroll
    for (int off = 32; off > 0; off >>= 1)
        acc += __shfl_down(acc, off, 64);

    __shared__ float ws[4];
    const int lane = threadIdx.x & 63;
    const int wid  = threadIdx.x >> 6;
    if (lane == 0) ws[wid] = acc;
    __syncthreads();
    if (threadIdx.x == 0)
        partials[blockIdx.x] = (ws[0] + ws[1]) + (ws[2] + ws[3]);
}

// ---------------------------------------------------------------------------
// Kernel 2: voxel reconstruction, 2 voxels/thread (f32x2 packed math).
// w = exp(1/dist) via 1 rsq + degree-6 poly (no exp trans op).
// Grid: NB*VCNT/512 = 1024 blocks (4/CU, 16 waves/CU).
// ---------------------------------------------------------------------------
__global__ __launch_bounds__(256) void recon_kernel(
    const float* __restrict__ transforms,
    const int*   __restrict__ sidx,
    const float* __restrict__ partials,
    float*       __restrict__ out)
{
    __shared__ float4 ct[NT];  // x, y, z, mean

    const int b  = blockIdx.x >> 9;                           // 512 blocks/batch
    const int v0 = ((blockIdx.x & 511) << 9) + (threadIdx.x << 1);

    if (threadIdx.x < NT) {
        const int idx = sidx[b * NT + threadIdx.x];
        const float* tr = transforms + (size_t)(b * NT + idx) * 6;
        const float* pp = partials   + (size_t)(b * NT + idx) * 8;
        float m = 0.0f;
#pragma unroll
        for (int i = 0; i < 8; ++i) m += pp[i];
        ct[threadIdx.x] = make_float4(tr[0], tr[1], tr[2],
                                      m * (1.0f / (float)HWPIX));
    }
    __syncthreads();

    const float fx = (float)(v0 >> 12);
    const float fy = (float)((v0 >> 6) & 63);
    const float fz = (float)(v0 & 63);        // v0 even -> pair in same row

    const f32x2 fx2 = {fx, fx};
    const f32x2 fy2 = {fy, fy};
    const f32x2 fz2 = {fz, fz + 1.0f};

    f32x2 wsum = {0.0f, 0.0f};
    f32x2 acc  = {0.0f, 0.0f};

#pragma unroll 4
    for (int t = 0; t < NT; ++t) {
        float4 c = ct[t];                 // uniform addr -> LDS broadcast
        f32x2 dx = fx2 - c.x;
        f32x2 dy = fy2 - c.y;
        f32x2 dz = fz2 - c.z;
        f32x2 d2 = dx * dx + dy * dy + dz * dz;   // pk_mul + 2x pk_fma
        f32x2 u;
        u.x = fast_rsq(d2.x);             // 1/dist
        u.y = fast_rsq(d2.y);
        f32x2 tt = u - PC;
        f32x2 w = tt * PA6 + PA5;         // Horner, 6x pk_fma
        w = w * tt + PA4;
        w = w * tt + PA3;
        w = w * tt + PA2;
        w = w * tt + PA1;
        w = w * tt + PA0;
        wsum += w;
        acc  += w * c.w;
    }

    float2 o;
    o.x = acc.x / wsum.x;
    o.y = acc.y / wsum.y;
    *(float2*)(out + (size_t)b * VCNT + v0) = o;
}

// ---------------------------------------------------------------------------
extern "C" void kernel_launch(void* const* d_in, const int* in_sizes, int n_in,
                              void* d_out, int out_size, void* d_ws, size_t ws_size,
                              hipStream_t stream)
{
    const float* slices     = (const float*)d_in[0];  // (2,128,1,256,256) f32
    const float* transforms = (const float*)d_in[1];  // (2,128,6) f32
    const int*   sidx       = (const int*)d_in[2];    // (2,128) i32
    float* out = (float*)d_out;                       // (2,1,64,64,64) f32

    int*   flags    = (int*)d_ws;                     // 256 ints
    float* partials = (float*)d_ws + 256;             // 2048 floats

    flags_kernel<<<1, 256, 0, stream>>>(sidx, flags);
    slice_partial_kernel<<<NB * NT * 8, 256, 0, stream>>>(slices, flags, partials);
    recon_kernel<<<NB * VCNT / 512, 256, 0, stream>>>(transforms, sidx, partials, out);
}

// Round 4
// 29.559 us; speedup vs baseline: 1.3105x; 1.3105x over previous
//
#include <hip/hip_runtime.h>

#define VCNT 262144           // 64^3
#define NB 2
#define NT 128
#define HWPIX 65536           // 1*256*256
#define LN2 0.69314718055994531f

typedef float f32x2 __attribute__((ext_vector_type(2)));

static __device__ __forceinline__ float fast_exp2(float x) {
#if __has_builtin(__builtin_amdgcn_exp2f)
    return __builtin_amdgcn_exp2f(x);
#else
    float r; asm("v_exp_f32 %0, %1" : "=v"(r) : "v"(x)); return r;
#endif
}
static __device__ __forceinline__ float fast_rsq(float x) {
#if __has_builtin(__builtin_amdgcn_rsqf)
    return __builtin_amdgcn_rsqf(x);
#else
    float r; asm("v_rsq_f32 %0, %1" : "=v"(r) : "v"(x)); return r;
#endif
}

// ---------------------------------------------------------------------------
// Kernel 1: partial slice sums, needed slices only. 8 blocks/slice = 2048.
// Membership test done in-kernel (no extra launch): slice s=(b,t) is needed
// iff t appears in sidx[b,:]. ~37% of slices early-exit (block-uniform).
// ---------------------------------------------------------------------------
__global__ __launch_bounds__(256) void slice_partial_kernel(
    const float* __restrict__ slices, const int* __restrict__ sidx,
    float* __restrict__ partials)
{
    const int s   = blockIdx.x >> 3;   // 0..255
    const int b   = s >> 7;
    const int tsl = s & 127;

    __shared__ int needed;
    if (threadIdx.x == 0) needed = 0;
    __syncthreads();
    if (threadIdx.x < NT && sidx[(b << 7) + threadIdx.x] == tsl) needed = 1;
    __syncthreads();
    if (!needed) return;               // uniform across block

    const int j = blockIdx.x & 7;
    const float4* p = (const float4*)(slices + (size_t)s * HWPIX) + j * 2048;

    float acc = 0.0f;
#pragma unroll
    for (int i = 0; i < 8; ++i) {
        float4 v = p[i * 256 + threadIdx.x];
        acc += (v.x + v.y) + (v.z + v.w);
    }
#pragma unroll
    for (int off = 32; off > 0; off >>= 1)
        acc += __shfl_down(acc, off, 64);

    __shared__ float ws[4];
    const int lane = threadIdx.x & 63;
    const int wid  = threadIdx.x >> 6;
    if (lane == 0) ws[wid] = acc;
    __syncthreads();
    if (threadIdx.x == 0)
        partials[blockIdx.x] = (ws[0] + ws[1]) + (ws[2] + ws[3]);
}

// ---------------------------------------------------------------------------
// Kernel 2: voxel reconstruction with duplicate-index compression.
// w and mean depend only on u=sidx[t], so group duplicates:
//   recon = sum_u k_u*w_u*m_u / sum_u k_u*w_u   over n unique u (~81 of 128).
// Prologue (threads 0..127): multiplicity + first-occurrence scan, ballot
// prefix compaction into LDS. Inner loop: n iters, exp2(rsq) weights,
// 2 voxels/thread packed f32x2.
// ---------------------------------------------------------------------------
__global__ __launch_bounds__(256) void recon_kernel(
    const float* __restrict__ transforms,
    const int*   __restrict__ sidx,
    const float* __restrict__ partials,
    float*       __restrict__ out)
{
    __shared__ float4 ct[NT];   // LN2*x, LN2*y, LN2*z, k*mean
    __shared__ float  kk[NT];   // k (multiplicity)
    __shared__ int    wcnt[2];
    __shared__ int    ncnt;

    const int tid = threadIdx.x;
    const int b   = blockIdx.x >> 9;                     // 512 blocks/batch
    const int v0  = ((blockIdx.x & 511) << 9) + (tid << 1);

    int u = 0, k = 0, first = 0;
    if (tid < NT) {
        u = sidx[(b << 7) + tid];
        first = 1;
        for (int j = 0; j < NT; ++j) {
            const int m = (sidx[(b << 7) + j] == u) ? 1 : 0;
            k += m;
            if (m && j < tid) first = 0;
        }
    }
    const unsigned long long mask = __ballot(first);
    const int lane = tid & 63;
    const int wid  = tid >> 6;
    if (tid < NT && lane == 0) wcnt[wid] = (int)__popcll(mask);
    __syncthreads();
    if (first) {
        const int pos = (int)__popcll(mask & ((1ull << lane) - 1ull))
                      + (wid ? wcnt[0] : 0);
        const float* tr = transforms + (size_t)((b << 7) + u) * 6;
        const float* pp = partials   + (size_t)((b << 7) + u) * 8;
        float m = 0.0f;
#pragma unroll
        for (int i = 0; i < 8; ++i) m += pp[i];
        m *= (1.0f / (float)HWPIX);
        const float fk = (float)k;
        ct[pos] = make_float4(tr[0] * LN2, tr[1] * LN2, tr[2] * LN2, fk * m);
        kk[pos] = fk;
    }
    if (tid == 0) ncnt = wcnt[0] + wcnt[1];
    __syncthreads();
    const int n = ncnt;

    const float fx = (float)(v0 >> 12) * LN2;
    const float fy = (float)((v0 >> 6) & 63) * LN2;
    const float fz = (float)(v0 & 63) * LN2;   // v0 even -> pair in same row

    const f32x2 fx2 = {fx, fx};
    const f32x2 fy2 = {fy, fy};
    const f32x2 fz2 = {fz, fz + LN2};

    f32x2 wsum = {0.0f, 0.0f};
    f32x2 acc  = {0.0f, 0.0f};

#pragma unroll 4
    for (int t = 0; t < n; ++t) {
        const float4 c  = ct[t];          // uniform addr -> LDS broadcast
        const float  kf = kk[t];
        f32x2 dx = fx2 - c.x;
        f32x2 dy = fy2 - c.y;
        f32x2 dz = fz2 - c.z;
        f32x2 d2 = dx * dx + dy * dy + dz * dz;   // pk_mul + 2x pk_fma
        f32x2 w;
        w.x = fast_exp2(fast_rsq(d2.x));  // e^(1/dist): coords pre-scaled ln2
        w.y = fast_exp2(fast_rsq(d2.y));
        wsum += w * kf;                   // sum_u k*w      (pk_fma)
        acc  += w * c.w;                  // sum_u k*w*mean (pk_fma)
    }

    float2 o;
    o.x = acc.x / wsum.x;
    o.y = acc.y / wsum.y;
    *(float2*)(out + (size_t)b * VCNT + v0) = o;
}

// ---------------------------------------------------------------------------
extern "C" void kernel_launch(void* const* d_in, const int* in_sizes, int n_in,
                              void* d_out, int out_size, void* d_ws, size_t ws_size,
                              hipStream_t stream)
{
    const float* slices     = (const float*)d_in[0];  // (2,128,1,256,256) f32
    const float* transforms = (const float*)d_in[1];  // (2,128,6) f32
    const int*   sidx       = (const int*)d_in[2];    // (2,128) i32
    float* out      = (float*)d_out;                  // (2,1,64,64,64) f32
    float* partials = (float*)d_ws;                   // 2048 floats scratch

    slice_partial_kernel<<<NB * NT * 8, 256, 0, stream>>>(slices, sidx, partials);
    recon_kernel<<<NB * VCNT / 512, 256, 0, stream>>>(transforms, sidx, partials, out);
}

// Round 5
// 26.643 us; speedup vs baseline: 1.4540x; 1.1094x over previous
//
#include <hip/hip_runtime.h>

#define VCNT 262144           // 64^3
#define NB 2
#define NT 128
#define HWPIX 65536           // 1*256*256
#define LN2  0.69314718055994531f
#define LN2X2 1.38629436111989062f

typedef float f32x2 __attribute__((ext_vector_type(2)));

static __device__ __forceinline__ float fast_exp2(float x) {
#if __has_builtin(__builtin_amdgcn_exp2f)
    return __builtin_amdgcn_exp2f(x);
#else
    float r; asm("v_exp_f32 %0, %1" : "=v"(r) : "v"(x)); return r;
#endif
}
static __device__ __forceinline__ float fast_rsq(float x) {
#if __has_builtin(__builtin_amdgcn_rsqf)
    return __builtin_amdgcn_rsqf(x);
#else
    float r; asm("v_rsq_f32 %0, %1" : "=v"(r) : "v"(x)); return r;
#endif
}

// ---------------------------------------------------------------------------
// Kernel 1: partial slice sums, needed slices only. 8 blocks/slice = 2048.
// Membership tested in-kernel; ~37% of slices early-exit (block-uniform).
// ---------------------------------------------------------------------------
__global__ __launch_bounds__(256) void slice_partial_kernel(
    const float* __restrict__ slices, const int* __restrict__ sidx,
    float* __restrict__ partials)
{
    const int s   = blockIdx.x >> 3;   // 0..255
    const int b   = s >> 7;
    const int tsl = s & 127;

    __shared__ int needed;
    if (threadIdx.x == 0) needed = 0;
    __syncthreads();
    if (threadIdx.x < NT && sidx[(b << 7) + threadIdx.x] == tsl) needed = 1;
    __syncthreads();
    if (!needed) return;               // uniform across block

    const int j = blockIdx.x & 7;
    const float4* p = (const float4*)(slices + (size_t)s * HWPIX) + j * 2048;

    float acc = 0.0f;
#pragma unroll
    for (int i = 0; i < 8; ++i) {
        float4 v = p[i * 256 + threadIdx.x];
        acc += (v.x + v.y) + (v.z + v.w);
    }
#pragma unroll
    for (int off = 32; off > 0; off >>= 1)
        acc += __shfl_down(acc, off, 64);

    __shared__ float ws[4];
    const int lane = threadIdx.x & 63;
    const int wid  = threadIdx.x >> 6;
    if (lane == 0) ws[wid] = acc;
    __syncthreads();
    if (threadIdx.x == 0)
        partials[blockIdx.x] = (ws[0] + ws[1]) + (ws[2] + ws[3]);
}

// ---------------------------------------------------------------------------
// Kernel 2: voxel reconstruction.
//  - duplicate-index compression via O(1) LDS-atomic dedup (thread tid owns
//    slice-id tid: multiplicity k=cnt[tid], ballot prefix -> compact pos)
//  - 4 z-consecutive voxels/thread; dx^2+dy^2 and the LDS reads amortized
//    over 4 voxels, dz advanced incrementally (+2*ln2, coords ln2-prescaled
//    so w = exp(1/dist) = exp2(rsq(d2))).
// Grid: NB*VCNT/1024 = 512 blocks x 256 threads (2 waves/SIMD).
// ---------------------------------------------------------------------------
__global__ __launch_bounds__(256) void recon_kernel(
    const float* __restrict__ transforms,
    const int*   __restrict__ sidx,
    const float* __restrict__ partials,
    float*       __restrict__ out)
{
    __shared__ float4 ct[NT];   // LN2*x, LN2*y, LN2*z, k*mean
    __shared__ float  kk[NT];   // k (multiplicity)
    __shared__ int    cnt[NT];
    __shared__ int    wcnt[2];
    __shared__ int    ncnt;

    const int tid = threadIdx.x;
    const int b   = blockIdx.x >> 8;                       // 256 blocks/batch
    const int v0  = ((blockIdx.x & 255) << 10) + (tid << 2);

    if (tid < NT) cnt[tid] = 0;
    __syncthreads();
    if (tid < NT) atomicAdd(&cnt[sidx[(b << 7) + tid]], 1);
    __syncthreads();

    const int  k      = (tid < NT) ? cnt[tid] : 0;
    const bool neededf = (k > 0);
    const unsigned long long mask = __ballot(neededf);
    const int lane = tid & 63;
    const int wid  = tid >> 6;
    if (tid < NT && lane == 0) wcnt[wid] = (int)__popcll(mask);
    __syncthreads();
    if (neededf) {
        const int pos = (int)__popcll(mask & ((1ull << lane) - 1ull))
                      + (wid ? wcnt[0] : 0);
        const float* tr = transforms + (size_t)((b << 7) + tid) * 6;
        const float* pp = partials   + (size_t)((b << 7) + tid) * 8;
        float m = 0.0f;
#pragma unroll
        for (int i = 0; i < 8; ++i) m += pp[i];
        m *= (1.0f / (float)HWPIX);
        const float fk = (float)k;
        ct[pos] = make_float4(tr[0] * LN2, tr[1] * LN2, tr[2] * LN2, fk * m);
        kk[pos] = fk;
    }
    if (tid == 0) ncnt = wcnt[0] + wcnt[1];
    __syncthreads();
    const int n = ncnt;

    const float fx  = (float)(v0 >> 12) * LN2;
    const float fy  = (float)((v0 >> 6) & 63) * LN2;
    const float fz0 = (float)(v0 & 63) * LN2;
    const f32x2 fzp = {fz0, fz0 + LN2};     // even/odd z pair

    f32x2 wsumA = {0.0f, 0.0f}, accA = {0.0f, 0.0f};   // z, z+1
    f32x2 wsumB = {0.0f, 0.0f}, accB = {0.0f, 0.0f};   // z+2, z+3

#pragma unroll 2
    for (int t = 0; t < n; ++t) {
        const float4 c  = ct[t];            // uniform addr -> LDS broadcast
        const float  kf = kk[t];
        const float dx = fx - c.x;
        const float dy = fy - c.y;
        const float base = fmaf(dy, dy, dx * dx);
        f32x2 dz0 = fzp - c.z;              // pair (z, z+1)
        f32x2 d2a = dz0 * dz0 + base;
        f32x2 dz1 = dz0 + LN2X2;            // pair (z+2, z+3)
        f32x2 d2b = dz1 * dz1 + base;

        f32x2 wA, wB;
        wA.x = fast_exp2(fast_rsq(d2a.x));  // e^(1/dist), coords ln2-scaled
        wA.y = fast_exp2(fast_rsq(d2a.y));
        wB.x = fast_exp2(fast_rsq(d2b.x));
        wB.y = fast_exp2(fast_rsq(d2b.y));

        wsumA += wA * kf;                   // sum_u k*w
        accA  += wA * c.w;                  // sum_u k*w*mean
        wsumB += wB * kf;
        accB  += wB * c.w;
    }

    float4 o;
    o.x = accA.x / wsumA.x;
    o.y = accA.y / wsumA.y;
    o.z = accB.x / wsumB.x;
    o.w = accB.y / wsumB.y;
    *(float4*)(out + (size_t)b * VCNT + v0) = o;
}

// ---------------------------------------------------------------------------
extern "C" void kernel_launch(void* const* d_in, const int* in_sizes, int n_in,
                              void* d_out, int out_size, void* d_ws, size_t ws_size,
                              hipStream_t stream)
{
    const float* slices     = (const float*)d_in[0];  // (2,128,1,256,256) f32
    const float* transforms = (const float*)d_in[1];  // (2,128,6) f32
    const int*   sidx       = (const int*)d_in[2];    // (2,128) i32
    float* out      = (float*)d_out;                  // (2,1,64,64,64) f32
    float* partials = (float*)d_ws;                   // 2048 floats scratch

    slice_partial_kernel<<<NB * NT * 8, 256, 0, stream>>>(slices, sidx, partials);
    recon_kernel<<<NB * VCNT / 1024, 256, 0, stream>>>(transforms, sidx, partials, out);
}

// Round 6
// 26.256 us; speedup vs baseline: 1.4754x; 1.0148x over previous
//
#include <hip/hip_runtime.h>

#define VCNT 262144           // 64^3
#define NB 2
#define NT 128
#define HWPIX 65536           // 1*256*256
#define LN2  0.69314718055994531f
#define LN2X2 1.38629436111989062f

typedef float f32x2 __attribute__((ext_vector_type(2)));

static __device__ __forceinline__ float fast_exp2(float x) {
#if __has_builtin(__builtin_amdgcn_exp2f)
    return __builtin_amdgcn_exp2f(x);
#else
    float r; asm("v_exp_f32 %0, %1" : "=v"(r) : "v"(x)); return r;
#endif
}
static __device__ __forceinline__ float fast_rsq(float x) {
#if __has_builtin(__builtin_amdgcn_rsqf)
    return __builtin_amdgcn_rsqf(x);
#else
    float r; asm("v_rsq_f32 %0, %1" : "=v"(r) : "v"(x)); return r;
#endif
}

// ---------------------------------------------------------------------------
// Kernel 1: partial slice sums, needed slices only. 8 blocks/slice = 2048.
// Membership tested in-kernel; ~37% of slices early-exit (block-uniform).
// ---------------------------------------------------------------------------
__global__ __launch_bounds__(256) void slice_partial_kernel(
    const float* __restrict__ slices, const int* __restrict__ sidx,
    float* __restrict__ partials)
{
    const int s   = blockIdx.x >> 3;   // 0..255
    const int b   = s >> 7;
    const int tsl = s & 127;

    __shared__ int needed;
    if (threadIdx.x == 0) needed = 0;
    __syncthreads();
    if (threadIdx.x < NT && sidx[(b << 7) + threadIdx.x] == tsl) needed = 1;
    __syncthreads();
    if (!needed) return;               // uniform across block

    const int j = blockIdx.x & 7;
    const float4* p = (const float4*)(slices + (size_t)s * HWPIX) + j * 2048;

    float acc = 0.0f;
#pragma unroll
    for (int i = 0; i < 8; ++i) {
        float4 v = p[i * 256 + threadIdx.x];
        acc += (v.x + v.y) + (v.z + v.w);
    }
#pragma unroll
    for (int off = 32; off > 0; off >>= 1)
        acc += __shfl_down(acc, off, 64);

    __shared__ float ws[4];
    const int lane = threadIdx.x & 63;
    const int wid  = threadIdx.x >> 6;
    if (lane == 0) ws[wid] = acc;
    __syncthreads();
    if (threadIdx.x == 0)
        partials[blockIdx.x] = (ws[0] + ws[1]) + (ws[2] + ws[3]);
}

// ---------------------------------------------------------------------------
// Kernel 2: voxel reconstruction.
//  - O(1) LDS-atomic dedup of duplicate slice indices (n unique u of 128)
//  - 4 z-consecutive voxels per lane-PAIR: lanes l and l^32 of a wave work
//    on the same voxel quad but interleaved halves of the u-table
//    (t = g, g+2, ...), combined at the end via __shfl_xor(.,32).
//    -> same amortization as R5 but 2x the waves (4/SIMD) for latency hiding.
//  - coords pre-scaled by ln2 so w = exp(1/dist) = exp2(rsq(d2)).
// Grid: NB*VCNT/512 = 1024 blocks x 256 threads (4 waves/SIMD).
// ---------------------------------------------------------------------------
__global__ __launch_bounds__(256) void recon_kernel(
    const float* __restrict__ transforms,
    const int*   __restrict__ sidx,
    const float* __restrict__ partials,
    float*       __restrict__ out)
{
    __shared__ float4 ct[NT];   // LN2*x, LN2*y, LN2*z, k*mean
    __shared__ float  kk[NT];   // k (multiplicity)
    __shared__ int    cnt[NT];
    __shared__ int    wcnt[2];
    __shared__ int    ncnt;

    const int tid  = threadIdx.x;
    const int lane = tid & 63;
    const int wid  = tid >> 6;
    const int b    = blockIdx.x >> 9;                      // 512 blocks/batch

    // ---- dedup prologue (threads 0..127), O(1) via LDS atomics ----
    if (tid < NT) cnt[tid] = 0;
    __syncthreads();
    if (tid < NT) atomicAdd(&cnt[sidx[(b << 7) + tid]], 1);
    __syncthreads();

    const int  k       = (tid < NT) ? cnt[tid] : 0;
    const bool neededf = (k > 0);
    const unsigned long long mask = __ballot(neededf);
    if (tid < NT && lane == 0) wcnt[wid] = (int)__popcll(mask);
    __syncthreads();
    if (neededf) {
        const int pos = (int)__popcll(mask & ((1ull << lane) - 1ull))
                      + (wid ? wcnt[0] : 0);
        const float* tr = transforms + (size_t)((b << 7) + tid) * 6;
        const float* pp = partials   + (size_t)((b << 7) + tid) * 8;
        float m = 0.0f;
#pragma unroll
        for (int i = 0; i < 8; ++i) m += pp[i];
        m *= (1.0f / (float)HWPIX);
        const float fk = (float)k;
        ct[pos] = make_float4(tr[0] * LN2, tr[1] * LN2, tr[2] * LN2, fk * m);
        kk[pos] = fk;
    }
    if (tid == 0) ncnt = wcnt[0] + wcnt[1];
    __syncthreads();
    const int n = ncnt;

    // ---- voxel quad for this lane-pair ----
    const int g    = (lane >> 5) & 1;                 // u-table half
    const int quad = (wid << 5) + (lane & 31);        // 0..127 within block
    const int v0   = ((blockIdx.x & 511) << 9) + (quad << 2);

    const float fx  = (float)(v0 >> 12) * LN2;
    const float fy  = (float)((v0 >> 6) & 63) * LN2;
    const float fz0 = (float)(v0 & 63) * LN2;
    const f32x2 fzp = {fz0, fz0 + LN2};               // even/odd z pair

    f32x2 wsumA = {0.0f, 0.0f}, accA = {0.0f, 0.0f};  // z, z+1
    f32x2 wsumB = {0.0f, 0.0f}, accB = {0.0f, 0.0f};  // z+2, z+3

#pragma unroll 2
    for (int t = g; t < n; t += 2) {
        const float4 c  = ct[t];          // uniform per half-wave -> broadcast
        const float  kf = kk[t];
        const float dx = fx - c.x;
        const float dy = fy - c.y;
        const float base = fmaf(dy, dy, dx * dx);
        f32x2 dz0 = fzp - c.z;            // pair (z, z+1)
        f32x2 d2a = dz0 * dz0 + base;
        f32x2 dz1 = dz0 + LN2X2;          // pair (z+2, z+3)
        f32x2 d2b = dz1 * dz1 + base;

        f32x2 wA, wB;
        wA.x = fast_exp2(fast_rsq(d2a.x));   // e^(1/dist), coords ln2-scaled
        wA.y = fast_exp2(fast_rsq(d2a.y));
        wB.x = fast_exp2(fast_rsq(d2b.x));
        wB.y = fast_exp2(fast_rsq(d2b.y));

        wsumA += wA * kf;                 // sum_u k*w
        accA  += wA * c.w;                // sum_u k*w*mean
        wsumB += wB * kf;
        accB  += wB * c.w;
    }

    // ---- combine the two u-halves (partner lane l^32) ----
    wsumA.x += __shfl_xor(wsumA.x, 32, 64);
    wsumA.y += __shfl_xor(wsumA.y, 32, 64);
    wsumB.x += __shfl_xor(wsumB.x, 32, 64);
    wsumB.y += __shfl_xor(wsumB.y, 32, 64);
    accA.x  += __shfl_xor(accA.x, 32, 64);
    accA.y  += __shfl_xor(accA.y, 32, 64);
    accB.x  += __shfl_xor(accB.x, 32, 64);
    accB.y  += __shfl_xor(accB.y, 32, 64);

    if ((lane >> 5) == 0) {               // one writer per voxel quad
        float4 o;
        o.x = accA.x / wsumA.x;
        o.y = accA.y / wsumA.y;
        o.z = accB.x / wsumB.x;
        o.w = accB.y / wsumB.y;
        *(float4*)(out + (size_t)b * VCNT + v0) = o;
    }
}

// ---------------------------------------------------------------------------
extern "C" void kernel_launch(void* const* d_in, const int* in_sizes, int n_in,
                              void* d_out, int out_size, void* d_ws, size_t ws_size,
                              hipStream_t stream)
{
    const float* slices     = (const float*)d_in[0];  // (2,128,1,256,256) f32
    const float* transforms = (const float*)d_in[1];  // (2,128,6) f32
    const int*   sidx       = (const int*)d_in[2];    // (2,128) i32
    float* out      = (float*)d_out;                  // (2,1,64,64,64) f32
    float* partials = (float*)d_ws;                   // 2048 floats scratch

    slice_partial_kernel<<<NB * NT * 8, 256, 0, stream>>>(slices, sidx, partials);
    recon_kernel<<<NB * VCNT / 512, 256, 0, stream>>>(transforms, sidx, partials, out);
}